// Round 10
// baseline (428.965 us; speedup 1.0000x reference)
//
#include <hip/hip_runtime.h>
#include <math.h>

#define N_NODES 50000
#define DIM 256
#define NE 300000
#define NEV 100000
#define BM 64
#define BK 64
#define NSLOT 8
#define GRID_PER ((N_NODES + BM - 1) / BM)   // 782
#define SP_W_BLOCKS (4 * DIM)                // 1024 W-prep blocks
#define SP_X_BLOCKS 1024                     // xb-convert blocks

typedef float f32x4 __attribute__((ext_vector_type(4)));
typedef short s16x8 __attribute__((ext_vector_type(8)));

__device__ inline unsigned short f2bf(float f) {
    unsigned u = __float_as_uint(f);
    u += 0x7FFF + ((u >> 16) & 1);            // round-to-nearest-even
    return (unsigned short)(u >> 16);
}
__device__ inline float bf2f(unsigned short s) {
    return __uint_as_float(((unsigned)s) << 16);
}
// swizzled halfword offset inside a [R][64] bf16 tile (16B granules, T2 XOR)
__device__ inline int swz(int row, int kg) {
    return row * BK + ((kg ^ (row & 7)) << 3);
}
// async 16B global->LDS (linear dest; swizzle lives in the SOURCE layout)
__device__ inline void gl16(const unsigned short* g, unsigned short* l) {
    __builtin_amdgcn_global_load_lds(
        (const __attribute__((address_space(1))) void*)g,
        (__attribute__((address_space(3))) void*)l, 16, 0, 0);
}
// pre-swizzled h destination offset for (node, lane) -> lane's 4 cols
__device__ inline int hdst(int node, int lane) {
    return ((lane >> 4) << 6) + (((((lane >> 1) & 7)) ^ (node & 7)) << 3)
         + ((lane & 1) << 2);
}

// ---------------------------------------------------------------------------
// hist: dst-degree histogram for both edge sets (first launch; feeds scan)
// ---------------------------------------------------------------------------
__global__ __launch_bounds__(256) void hist_kernel(
    const int* __restrict__ ei, const int* __restrict__ vi,
    int* __restrict__ degD, int* __restrict__ degU)
{
    int i = blockIdx.x * blockDim.x + threadIdx.x;
    if (i < NE) atomicAdd(&degD[ei[NE + i]], 1);
    else if (i < NE + NEV) { int j = i - NE; atomicAdd(&degU[vi[NEV + j]], 1); }
}

// ---------------------------------------------------------------------------
// scanprep: blocks 0-1 = exclusive scans (D/U); blocks 2.. = W-prep + xb.
// Fills the otherwise-idle GPU during the serial scans.
// ---------------------------------------------------------------------------
__global__ __launch_bounds__(1024) void scanprep_kernel(
    int* __restrict__ offD, int* __restrict__ curD,
    int* __restrict__ offU, int* __restrict__ curU,
    const float* __restrict__ W1d, const float* __restrict__ W2d,
    const float* __restrict__ W1u, const float* __restrict__ W2u,
    unsigned short* __restrict__ Wt,
    const float* __restrict__ x, unsigned short* __restrict__ xb)
{
    int blk = blockIdx.x;
    if (blk < 2) {
        int* deg_offsets = (blk == 0) ? offD : offU;
        int* cursor      = (blk == 0) ? curD : curU;
        int E            = (blk == 0) ? NE : NEV;
        __shared__ int part[1024];
        int t = threadIdx.x;
        const int CH = (N_NODES + 1023) / 1024;
        int beg = t * CH;
        int end = min(beg + CH, N_NODES);
        int s = 0;
        for (int i = beg; i < end; i++) s += deg_offsets[i];
        part[t] = s;
        __syncthreads();
        for (int off = 1; off < 1024; off <<= 1) {
            int v = part[t];
            int u = (t >= off) ? part[t - off] : 0;
            __syncthreads();
            part[t] = v + u;
            __syncthreads();
        }
        int run = (t > 0) ? part[t - 1] : 0;
        for (int i = beg; i < end; i++) {
            int dv = deg_offsets[i];
            deg_offsets[i] = run;
            cursor[i] = run;
            run += dv;
        }
        if (t == 1023) deg_offsets[N_NODES] = E;
        return;
    }
    // prep blocks run with 1024 threads; use 256-thread slices
    int b = blk - 2;
    int t1024 = threadIdx.x;
    if (b < SP_W_BLOCKS / 4) {             // 256 blocks x 4 sub = 1024 W-cols
        int sub = t1024 >> 8, t = t1024 & 255;
        int bb = b * 4 + sub;              // 0..1023
        int w = bb >> 8, n = bb & 255;
        const float* W = (w == 0) ? W1d : (w == 1) ? W2d : (w == 2) ? W1u : W2u;
        int k0 = (t >> 6) << 6, kg = (t >> 3) & 7, j = t & 7;
        int src = k0 + ((kg ^ (n & 7)) << 3) + j;     // inverse-XOR source col
        Wt[(size_t)w * DIM * DIM + (size_t)n * DIM + t] =
            f2bf(W[(size_t)src * DIM + n]);
    } else {
        int idx = (b - SP_W_BLOCKS / 4) * 1024 + t1024;
        const int stride = SP_X_BLOCKS * 1024;
        const int total = N_NODES * (DIM / 8);
        for (int f = idx; f < total; f += stride) {
            float4 v0 = ((const float4*)x)[f * 2];
            float4 v1 = ((const float4*)x)[f * 2 + 1];
            s16x8 pk;
            pk[0] = f2bf(v0.x); pk[1] = f2bf(v0.y);
            pk[2] = f2bf(v0.z); pk[3] = f2bf(v0.w);
            pk[4] = f2bf(v1.x); pk[5] = f2bf(v1.y);
            pk[6] = f2bf(v1.z); pk[7] = f2bf(v1.w);
            *(s16x8*)(xb + (size_t)f * 8) = pk;
        }
    }
}

__global__ __launch_bounds__(256) void fill2_kernel(
    const int* __restrict__ ei, const int* __restrict__ vi,
    int* __restrict__ curD, int* __restrict__ curU,
    int2* __restrict__ pairsD, int2* __restrict__ pairsU)
{
    int i = blockIdx.x * blockDim.x + threadIdx.x;
    if (i < NE) {
        int s = ei[i], d = ei[NE + i];
        int pos = atomicAdd(&curD[d], 1);
        pairsD[pos] = make_int2(i, s);
    } else if (i < NE + NEV) {
        int j = i - NE;
        int s = vi[j], d = vi[NEV + j];
        int pos = atomicAdd(&curU[d], 1);
        pairsU[pos] = make_int2(j, s);
    }
}

// ---------------------------------------------------------------------------
// gather: D node -> full block (4 waves, edge parity mod 4);
//         U nodes -> 2 per block (2 waves each, parity mod 2).
// x rows read as bf16 (xb); emits h PRE-SWIZZLED for gemm1 gl16.
// ---------------------------------------------------------------------------
__device__ inline f32x4 ldnt4(const float* p) {
    return __builtin_nontemporal_load((const f32x4*)p);
}
__device__ inline f32x4 bf4f(ushort4 v) {
    f32x4 r;
    r.x = bf2f(v.x); r.y = bf2f(v.y); r.z = bf2f(v.z); r.w = bf2f(v.w);
    return r;
}
__device__ inline void acc_relu(f32x4& acc, f32x4 a, f32x4 b) {
    acc.x += fmaxf(a.x + b.x, 0.f);
    acc.y += fmaxf(a.y + b.y, 0.f);
    acc.z += fmaxf(a.z + b.z, 0.f);
    acc.w += fmaxf(a.w + b.w, 0.f);
}

__global__ __launch_bounds__(256) void gather2_kernel(
    const unsigned short* __restrict__ xb, const float* __restrict__ ea,
    const float* __restrict__ vea,
    const int* __restrict__ offD, const int2* __restrict__ pairsD,
    const int* __restrict__ offU, const int2* __restrict__ pairsU,
    const float* __restrict__ epsd, const float* __restrict__ epsu,
    unsigned short* __restrict__ hD, unsigned short* __restrict__ hU)
{
    __shared__ f32x4 part[4][64];
    int warp = threadIdx.x >> 6;          // 0..3
    int lane = threadIdx.x & 63;
    int cofs = lane * 4;
    bool downblk = blockIdx.x < N_NODES;

    int node, nway, way, slotn;
    const int* off; const int2* pairs; const float* eat; unsigned short* h;
    float epsv;
    if (downblk) {
        node = blockIdx.x; nway = 4; way = warp; slotn = 0;
        off = offD; pairs = pairsD; eat = ea; h = hD;
        epsv = 1.0f + epsd[0];
    } else {
        int ub = blockIdx.x - N_NODES;    // 0..24999
        slotn = warp >> 1;
        node = ub * 2 + slotn;
        nway = 2; way = warp & 1;
        off = offU; pairs = pairsU; eat = vea; h = hU;
        epsv = 1.0f + epsu[0];
    }

    int beg = off[node], end = off[node + 1];
    f32x4 acc = {0.f, 0.f, 0.f, 0.f};
    int p = beg + way;
    for (; p + nway < end; p += 2 * nway) {     // 2 edges in flight per wave
        int2 q0 = pairs[p], q1 = pairs[p + nway];
        ushort4 a0 = *(const ushort4*)(xb + (size_t)q0.y * DIM + cofs);
        f32x4 b0 = ldnt4(eat + (size_t)q0.x * DIM + cofs);
        ushort4 a1 = *(const ushort4*)(xb + (size_t)q1.y * DIM + cofs);
        f32x4 b1 = ldnt4(eat + (size_t)q1.x * DIM + cofs);
        acc_relu(acc, bf4f(a0), b0);
        acc_relu(acc, bf4f(a1), b1);
    }
    if (p < end) {
        int2 q0 = pairs[p];
        ushort4 a0 = *(const ushort4*)(xb + (size_t)q0.y * DIM + cofs);
        f32x4 b0 = ldnt4(eat + (size_t)q0.x * DIM + cofs);
        acc_relu(acc, bf4f(a0), b0);
    }
    if (way != 0) part[warp][lane] = acc;
    __syncthreads();
    if (way == 0) {
        if (downblk) {
            f32x4 o1 = part[1][lane], o2 = part[2][lane], o3 = part[3][lane];
            acc.x += o1.x + o2.x + o3.x;
            acc.y += o1.y + o2.y + o3.y;
            acc.z += o1.z + o2.z + o3.z;
            acc.w += o1.w + o2.w + o3.w;
        } else {
            f32x4 o = part[slotn * 2 + 1][lane];
            acc.x += o.x; acc.y += o.y; acc.z += o.z; acc.w += o.w;
        }
        f32x4 xv = bf4f(*(const ushort4*)(xb + (size_t)node * DIM + cofs));
        acc.x = fmaf(epsv, xv.x, acc.x);
        acc.y = fmaf(epsv, xv.y, acc.y);
        acc.z = fmaf(epsv, xv.z, acc.z);
        acc.w = fmaf(epsv, xv.w, acc.w);
        ushort4 pk;
        pk.x = f2bf(acc.x); pk.y = f2bf(acc.y);
        pk.z = f2bf(acc.z); pk.w = f2bf(acc.w);
        *(ushort4*)(h + (size_t)node * DIM + hdst(node, lane)) = pk;
    }
}

// ---------------------------------------------------------------------------
// FALLBACK: atomic scatter into f32 aggr + convert (pre-swizzled h out)
// ---------------------------------------------------------------------------
__global__ __launch_bounds__(256) void scatter_kernel(
    const float* __restrict__ x, const float* __restrict__ ea,
    const int* __restrict__ idx, int E, float* __restrict__ buf)
{
    int wid = blockIdx.x * (blockDim.x >> 6) + (threadIdx.x >> 6);
    int lane = threadIdx.x & 63;
    if (wid >= E) return;
    int s = idx[wid];
    int d = idx[E + wid];
    float4 a = ((const float4*)(x + (size_t)s * DIM))[lane];
    float4 b = ((const float4*)(ea + (size_t)wid * DIM))[lane];
    float* dst = buf + (size_t)d * DIM + lane * 4;
    atomicAdd(dst + 0, fmaxf(a.x + b.x, 0.f));
    atomicAdd(dst + 1, fmaxf(a.y + b.y, 0.f));
    atomicAdd(dst + 2, fmaxf(a.z + b.z, 0.f));
    atomicAdd(dst + 3, fmaxf(a.w + b.w, 0.f));
}

__global__ __launch_bounds__(256) void conv_kernel(
    const float* __restrict__ x, const float* __restrict__ aggr,
    const float* __restrict__ eps_p, unsigned short* __restrict__ h)
{
    float epsv = 1.0f + eps_p[0];
    int i = blockIdx.x * blockDim.x + threadIdx.x;
    const int total = N_NODES * 64;
    for (int f = i; f < total; f += gridDim.x * blockDim.x) {
        int node = f >> 6, lane = f & 63;
        size_t o = (size_t)node * DIM + lane * 4;
        float4 xv = *(const float4*)(x + o);
        float4 av = *(const float4*)(aggr + o);
        ushort4 pk;
        pk.x = f2bf(fmaf(epsv, xv.x, av.x));
        pk.y = f2bf(fmaf(epsv, xv.y, av.y));
        pk.z = f2bf(fmaf(epsv, xv.z, av.z));
        pk.w = f2bf(fmaf(epsv, xv.w, av.w));
        *(ushort4*)(h + (size_t)node * DIM + hdst(node, lane)) = pk;
    }
}

__global__ __launch_bounds__(256) void prep_fb_kernel(
    const float* __restrict__ W1d, const float* __restrict__ W2d,
    const float* __restrict__ W1u, const float* __restrict__ W2u,
    unsigned short* __restrict__ Wt,
    const float* __restrict__ x, unsigned short* __restrict__ xb)
{
    int b = blockIdx.x, t = threadIdx.x;
    if (b < SP_W_BLOCKS) {
        int w = b >> 8, n = b & 255;
        const float* W = (w == 0) ? W1d : (w == 1) ? W2d : (w == 2) ? W1u : W2u;
        int k0 = (t >> 6) << 6, kg = (t >> 3) & 7, j = t & 7;
        int src = k0 + ((kg ^ (n & 7)) << 3) + j;
        Wt[(size_t)w * DIM * DIM + (size_t)n * DIM + t] =
            f2bf(W[(size_t)src * DIM + n]);
    } else {
        int idx = (b - SP_W_BLOCKS) * 256 + t;
        const int stride = SP_X_BLOCKS * 256;
        const int total = N_NODES * (DIM / 8);
        for (int f = idx; f < total; f += stride) {
            float4 v0 = ((const float4*)x)[f * 2];
            float4 v1 = ((const float4*)x)[f * 2 + 1];
            s16x8 pk;
            pk[0] = f2bf(v0.x); pk[1] = f2bf(v0.y);
            pk[2] = f2bf(v0.z); pk[3] = f2bf(v0.w);
            pk[4] = f2bf(v1.x); pk[5] = f2bf(v1.y);
            pk[6] = f2bf(v1.z); pk[7] = f2bf(v1.w);
            *(s16x8*)(xb + (size_t)f * 8) = pk;
        }
    }
}

// ---------------------------------------------------------------------------
// MFMA GEMM stage 1 (BOTH paths): A and B staged via global_load_lds
// ---------------------------------------------------------------------------
__global__ __launch_bounds__(256) void gemm1_both(
    const unsigned short* __restrict__ hD, const unsigned short* __restrict__ hU,
    const unsigned short* __restrict__ Wt1d, const unsigned short* __restrict__ Wt1u,
    const float* __restrict__ b1d, const float* __restrict__ b1u,
    unsigned short* __restrict__ t1D, unsigned short* __restrict__ t1U,
    float* __restrict__ sumD, float* __restrict__ sqD,
    float* __restrict__ sumU, float* __restrict__ sqU)
{
    __shared__ unsigned short As[BM * BK];
    __shared__ unsigned short Bs[DIM * BK];
    int blk = blockIdx.x;
    bool down = blk < GRID_PER;
    int bb = down ? blk : blk - GRID_PER;
    const unsigned short* h  = down ? hD   : hU;
    const unsigned short* Wt = down ? Wt1d : Wt1u;
    const float* bias        = down ? b1d  : b1u;
    unsigned short* t1       = down ? t1D  : t1U;
    float* ssum              = down ? sumD : sumU;
    float* ssq               = down ? sqD  : sqU;

    int t = threadIdx.x;
    int w = t >> 6, l = t & 63, lrow = l & 15, kgrp = l >> 4;
    int row0 = bb * BM;

    f32x4 acc[16];
    #pragma unroll
    for (int i = 0; i < 16; ++i) acc[i] = (f32x4){0.f, 0.f, 0.f, 0.f};

    for (int k0 = 0; k0 < DIM; k0 += BK) {
        __syncthreads();
        #pragma unroll
        for (int it = 0; it < 2; ++it) {
            int g = it * 256 + t;
            gl16(h + (size_t)(row0 + (g >> 3)) * DIM + k0 + ((g & 7) << 3),
                 &As[g << 3]);
        }
        #pragma unroll
        for (int it = 0; it < 8; ++it) {
            int g = it * 256 + t;
            gl16(Wt + (size_t)(g >> 3) * DIM + k0 + ((g & 7) << 3),
                 &Bs[g << 3]);
        }
        __syncthreads();
        #pragma unroll
        for (int kk = 0; kk < 2; ++kk) {
            s16x8 af[4], bf[4];
            #pragma unroll
            for (int mi = 0; mi < 4; ++mi)
                af[mi] = *(const s16x8*)&As[swz(mi * 16 + lrow, kk * 4 + kgrp)];
            #pragma unroll
            for (int ni = 0; ni < 4; ++ni)
                bf[ni] = *(const s16x8*)&Bs[swz(w * 64 + ni * 16 + lrow, kk * 4 + kgrp)];
            #pragma unroll
            for (int mi = 0; mi < 4; ++mi)
                #pragma unroll
                for (int ni = 0; ni < 4; ++ni)
                    acc[mi * 4 + ni] = __builtin_amdgcn_mfma_f32_16x16x32_bf16(
                        af[mi], bf[ni], acc[mi * 4 + ni], 0, 0, 0);
        }
    }
    int slot = bb & (NSLOT - 1);
    #pragma unroll
    for (int ni = 0; ni < 4; ++ni) {
        int col = w * 64 + ni * 16 + lrow;
        float bv = bias[col];
        float s = 0.f, q = 0.f;
        #pragma unroll
        for (int mi = 0; mi < 4; ++mi) {
            #pragma unroll
            for (int r = 0; r < 4; ++r) {
                int grow = row0 + mi * 16 + kgrp * 4 + r;
                if (grow < N_NODES) {
                    float v = acc[mi * 4 + ni][r] + bv;
                    t1[(size_t)grow * DIM + col] = f2bf(v);
                    s += v; q += v * v;
                }
            }
        }
        s += __shfl_xor(s, 16); q += __shfl_xor(q, 16);
        s += __shfl_xor(s, 32); q += __shfl_xor(q, 32);
        if (kgrp == 0) {
            atomicAdd(&ssum[slot * DIM + col], s);
            atomicAdd(&ssq[slot * DIM + col], q);
        }
    }
}

// ---------------------------------------------------------------------------
// per-column BN params from NSLOT-sliced stats
// ---------------------------------------------------------------------------
__device__ inline void bn_finalize(
    const float* ssum, const float* ssq, const float* g, const float* b,
    float* scale, float* shift, int c)
{
    float s = 0.f, q = 0.f;
    #pragma unroll
    for (int k = 0; k < NSLOT; ++k) { s += ssum[k * DIM + c]; q += ssq[k * DIM + c]; }
    const float invN = 1.0f / (float)N_NODES;
    float mu = s * invN;
    float var = q * invN - mu * mu;
    float sc = g[c] * rsqrtf(var + 1e-5f);
    scale[c] = sc;
    shift[c] = b[c] - mu * sc;
}

// ---------------------------------------------------------------------------
// FUSED stage 2: BN1(LDS) -> GEMM D -> GEMM U -> out = x + C1 + C2 + stats.
// ---------------------------------------------------------------------------
__global__ __launch_bounds__(256) void gemm2_fused(
    const unsigned short* __restrict__ t1D, const unsigned short* __restrict__ t1U,
    const float* __restrict__ sumD, const float* __restrict__ sqD,
    const float* __restrict__ g1d, const float* __restrict__ bt1d,
    const float* __restrict__ sumU, const float* __restrict__ sqU,
    const float* __restrict__ g1u, const float* __restrict__ bt1u,
    const unsigned short* __restrict__ Wt2d, const unsigned short* __restrict__ Wt2u,
    const float* __restrict__ b2d, const float* __restrict__ b2u,
    const float* __restrict__ a1, const float* __restrict__ a2,
    const float* __restrict__ x, float* __restrict__ out,
    float* __restrict__ sumF, float* __restrict__ sqF)
{
    __shared__ unsigned short As[BM * BK];
    __shared__ unsigned short Bs[DIM * BK];
    __shared__ float scDl[DIM], shDl[DIM], scUl[DIM], shUl[DIM];
    int t = threadIdx.x;
    int w = t >> 6, l = t & 63, lrow = l & 15, kgrp = l >> 4;
    int bb = blockIdx.x;
    int row0 = bb * BM;

    bn_finalize(sumD, sqD, g1d, bt1d, scDl, shDl, t);
    bn_finalize(sumU, sqU, g1u, bt1u, scUl, shUl, t);
    float a1v = a1[0], a2v = a2[0];

    f32x4 acc[16], accO[16];
    #pragma unroll
    for (int i = 0; i < 16; ++i) acc[i] = (f32x4){0.f, 0.f, 0.f, 0.f};

    #pragma unroll
    for (int phase = 0; phase < 2; ++phase) {
        const unsigned short* t1 = phase == 0 ? t1D : t1U;
        const unsigned short* Wt = phase == 0 ? Wt2d : Wt2u;
        const float* scl = phase == 0 ? scDl : scUl;
        const float* shl = phase == 0 ? shDl : shUl;
        for (int k0 = 0; k0 < DIM; k0 += BK) {
            __syncthreads();
            #pragma unroll
            for (int it = 0; it < 8; ++it) {
                int g = it * 256 + t;
                gl16(Wt + (size_t)(g >> 3) * DIM + k0 + ((g & 7) << 3),
                     &Bs[g << 3]);
            }
            #pragma unroll
            for (int it = 0; it < 2; ++it) {
                int g = it * 256 + t, row = g >> 3, kg = g & 7;
                int gr = row0 + row;
                s16x8 pack = {0, 0, 0, 0, 0, 0, 0, 0};
                if (gr < N_NODES) {
                    s16x8 tv = *(const s16x8*)(t1 + (size_t)gr * DIM + k0 + kg * 8);
                    #pragma unroll
                    for (int j = 0; j < 8; ++j) {
                        int c = k0 + kg * 8 + j;
                        pack[j] = f2bf(fmaxf(fmaf(bf2f((unsigned short)tv[j]), scl[c], shl[c]), 0.f));
                    }
                }
                *(s16x8*)&As[swz(row, kg)] = pack;
            }
            __syncthreads();
            #pragma unroll
            for (int kk = 0; kk < 2; ++kk) {
                s16x8 af[4], bf[4];
                #pragma unroll
                for (int mi = 0; mi < 4; ++mi)
                    af[mi] = *(const s16x8*)&As[swz(mi * 16 + lrow, kk * 4 + kgrp)];
                #pragma unroll
                for (int ni = 0; ni < 4; ++ni)
                    bf[ni] = *(const s16x8*)&Bs[swz(w * 64 + ni * 16 + lrow, kk * 4 + kgrp)];
                #pragma unroll
                for (int mi = 0; mi < 4; ++mi)
                    #pragma unroll
                    for (int ni = 0; ni < 4; ++ni)
                        acc[mi * 4 + ni] = __builtin_amdgcn_mfma_f32_16x16x32_bf16(
                            af[mi], bf[ni], acc[mi * 4 + ni], 0, 0, 0);
            }
        }
        if (phase == 0) {
            #pragma unroll
            for (int ni = 0; ni < 4; ++ni) {
                float bv = b2d[w * 64 + ni * 16 + lrow];
                #pragma unroll
                for (int mi = 0; mi < 4; ++mi) {
                    #pragma unroll
                    for (int r = 0; r < 4; ++r)
                        accO[mi * 4 + ni][r] = a1v * (acc[mi * 4 + ni][r] + bv);
                    acc[mi * 4 + ni] = (f32x4){0.f, 0.f, 0.f, 0.f};
                }
            }
        }
    }

    int slot = bb & (NSLOT - 1);
    #pragma unroll
    for (int ni = 0; ni < 4; ++ni) {
        int col = w * 64 + ni * 16 + lrow;
        float bvU = b2u[col];
        float s = 0.f, q = 0.f;
        #pragma unroll
        for (int mi = 0; mi < 4; ++mi) {
            #pragma unroll
            for (int r = 0; r < 4; ++r) {
                int grow = row0 + mi * 16 + kgrp * 4 + r;
                if (grow < N_NODES) {
                    size_t o = (size_t)grow * DIM + col;
                    float v = x[o] + accO[mi * 4 + ni][r]
                            + a2v * (acc[mi * 4 + ni][r] + bvU);
                    out[o] = v;
                    s += v; q += v * v;
                }
            }
        }
        s += __shfl_xor(s, 16); q += __shfl_xor(q, 16);
        s += __shfl_xor(s, 32); q += __shfl_xor(q, 32);
        if (kgrp == 0) {
            atomicAdd(&sumF[slot * DIM + col], s);
            atomicAdd(&sqF[slot * DIM + col], q);
        }
    }
}

// ---------------------------------------------------------------------------
// final BN + ReLU with fused finalize
// ---------------------------------------------------------------------------
__global__ __launch_bounds__(256) void bnrelu_kernel(
    float* __restrict__ out,
    const float* __restrict__ sumF, const float* __restrict__ sqF,
    const float* __restrict__ bng, const float* __restrict__ bnb)
{
    __shared__ float scl[DIM], shl[DIM];
    bn_finalize(sumF, sqF, bng, bnb, scl, shl, threadIdx.x);
    __syncthreads();
    int idx = blockIdx.x * blockDim.x + threadIdx.x;
    const int total = N_NODES * (DIM / 4);
    for (int f = idx; f < total; f += gridDim.x * blockDim.x) {
        float4 v = ((float4*)out)[f];
        int c = (f * 4) & (DIM - 1);
        float4 sc = *(const float4*)(scl + c);
        float4 sh = *(const float4*)(shl + c);
        v.x = fmaxf(v.x * sc.x + sh.x, 0.0f);
        v.y = fmaxf(v.y * sc.y + sh.y, 0.0f);
        v.z = fmaxf(v.z * sc.z + sh.z, 0.0f);
        v.w = fmaxf(v.w * sc.w + sh.w, 0.0f);
        ((float4*)out)[f] = v;
    }
}

extern "C" void kernel_launch(void* const* d_in, const int* in_sizes, int n_in,
                              void* d_out, int out_size, void* d_ws, size_t ws_size,
                              hipStream_t stream)
{
    const float* x    = (const float*)d_in[0];
    const int*   ei   = (const int*)  d_in[1];
    const float* ea   = (const float*)d_in[2];
    const int*   vi   = (const int*)  d_in[3];
    const float* vea  = (const float*)d_in[4];
    const float* epsd = (const float*)d_in[5];
    const float* W1d  = (const float*)d_in[6];
    const float* b1d  = (const float*)d_in[7];
    const float* g1d  = (const float*)d_in[8];
    const float* bt1d = (const float*)d_in[9];
    const float* W2d  = (const float*)d_in[10];
    const float* b2d  = (const float*)d_in[11];
    const float* epsu = (const float*)d_in[12];
    const float* W1u  = (const float*)d_in[13];
    const float* b1u  = (const float*)d_in[14];
    const float* g1u  = (const float*)d_in[15];
    const float* bt1u = (const float*)d_in[16];
    const float* W2u  = (const float*)d_in[17];
    const float* b2u  = (const float*)d_in[18];
    const float* bng  = (const float*)d_in[19];
    const float* bnb  = (const float*)d_in[20];
    const float* a1   = (const float*)d_in[21];
    const float* a2   = (const float*)d_in[22];

    float* out = (float*)d_out;

    // ---- workspace layout ----
    char* p = (char*)d_ws;
    unsigned short* hD  = (unsigned short*)p;  p += (size_t)N_NODES * DIM * 2;
    unsigned short* hU  = (unsigned short*)p;  p += (size_t)N_NODES * DIM * 2;
    unsigned short* t1D = (unsigned short*)p;  p += (size_t)N_NODES * DIM * 2;
    unsigned short* t1U = (unsigned short*)p;  p += (size_t)N_NODES * DIM * 2;
    unsigned short* xb  = (unsigned short*)p;  p += (size_t)N_NODES * DIM * 2;
    unsigned short* Wt  = (unsigned short*)p;  p += (size_t)4 * DIM * DIM * 2;
    // zeroed region: stats (6 slices) + offsets
    char* zero_base = p;
    float* stats = (float*)p;                  p += (size_t)6 * NSLOT * DIM * 4;
    int* offD = (int*)p;                       p += (size_t)(N_NODES + 1) * 4;
    int* offU = (int*)p;                       p += (size_t)(N_NODES + 1) * 4;
    size_t zero_bytes = (size_t)(p - zero_base);
    int* curD = (int*)p;                       p += (size_t)N_NODES * 4;
    int* curU = (int*)p;                       p += (size_t)N_NODES * 4;
    char* union_base = p;
    int2* pairsD = (int2*)p;                   p += (size_t)NE * 8;
    int2* pairsU = (int2*)p;                   p += (size_t)NEV * 8;
    size_t need_csr = (size_t)(p - (char*)d_ws);
    float* aggr = (float*)union_base;          // fallback-only, overlaps pairs
    size_t need_fb = (size_t)(union_base - (char*)d_ws) + (size_t)N_NODES * DIM * 4;
    bool use_csr = ws_size >= need_csr;

    float* sumD = stats;
    float* sqD  = stats + 1 * NSLOT * DIM;
    float* sumU = stats + 2 * NSLOT * DIM;
    float* sqU  = stats + 3 * NSLOT * DIM;
    float* sumF = stats + 4 * NSLOT * DIM;
    float* sqF  = stats + 5 * NSLOT * DIM;

    unsigned short* Wt1d = Wt;
    unsigned short* Wt2d = Wt + 1 * (size_t)DIM * DIM;
    unsigned short* Wt1u = Wt + 2 * (size_t)DIM * DIM;
    unsigned short* Wt2u = Wt + 3 * (size_t)DIM * DIM;

    hipMemsetAsync(zero_base, 0, zero_bytes, stream);

    if (use_csr) {
        hist_kernel<<<(NE + NEV + 255) / 256, 256, 0, stream>>>(ei, vi, offD, offU);
        scanprep_kernel<<<2 + SP_W_BLOCKS / 4 + SP_X_BLOCKS, 1024, 0, stream>>>(
            offD, curD, offU, curU, W1d, W2d, W1u, W2u, Wt, x, xb);
        fill2_kernel<<<(NE + NEV + 255) / 256, 256, 0, stream>>>(
            ei, vi, curD, curU, pairsD, pairsU);
        gather2_kernel<<<N_NODES + N_NODES / 2, 256, 0, stream>>>(
            xb, ea, vea, offD, pairsD, offU, pairsU, epsd, epsu, hD, hU);
    } else if (ws_size >= need_fb) {
        prep_fb_kernel<<<SP_W_BLOCKS + SP_X_BLOCKS, 256, 0, stream>>>(
            W1d, W2d, W1u, W2u, Wt, x, xb);
        hipMemsetAsync(aggr, 0, (size_t)N_NODES * DIM * 4, stream);
        scatter_kernel<<<(NE + 3) / 4, 256, 0, stream>>>(x, ea, ei, NE, aggr);
        conv_kernel<<<2048, 256, 0, stream>>>(x, aggr, epsd, hD);
        hipMemsetAsync(aggr, 0, (size_t)N_NODES * DIM * 4, stream);
        scatter_kernel<<<(NEV + 3) / 4, 256, 0, stream>>>(x, vea, vi, NEV, aggr);
        conv_kernel<<<2048, 256, 0, stream>>>(x, aggr, epsu, hU);
    }

    gemm1_both<<<2 * GRID_PER, 256, 0, stream>>>(
        hD, hU, Wt1d, Wt1u, b1d, b1u, t1D, t1U, sumD, sqD, sumU, sqU);

    gemm2_fused<<<GRID_PER, 256, 0, stream>>>(
        t1D, t1U, sumD, sqD, g1d, bt1d, sumU, sqU, g1u, bt1u,
        Wt2d, Wt2u, b2d, b2u, a1, a2, x, out, sumF, sqF);

    bnrelu_kernel<<<2048, 256, 0, stream>>>(out, sumF, sqF, bng, bnb);
}

// Round 11
// 412.592 us; speedup vs baseline: 1.0397x; 1.0397x over previous
//
#include <hip/hip_runtime.h>
#include <math.h>

#define N_NODES 50000
#define DIM 256
#define NE 300000
#define NEV 100000
#define BM 64
#define BK 64
#define NSLOT 8
#define GRID_PER ((N_NODES + BM - 1) / BM)   // 782
#define PREP_W_BLOCKS (4 * DIM)              // 1024
#define PREP_X_BLOCKS 1024
#define HIST_BLOCKS ((NE + NEV + 255) / 256) // 1563

typedef float f32x4 __attribute__((ext_vector_type(4)));
typedef short s16x8 __attribute__((ext_vector_type(8)));

__device__ inline unsigned short f2bf(float f) {
    unsigned u = __float_as_uint(f);
    u += 0x7FFF + ((u >> 16) & 1);            // round-to-nearest-even
    return (unsigned short)(u >> 16);
}
__device__ inline float bf2f(unsigned short s) {
    return __uint_as_float(((unsigned)s) << 16);
}
// swizzled halfword offset inside a [R][64] bf16 tile (16B granules, T2 XOR)
__device__ inline int swz(int row, int kg) {
    return row * BK + ((kg ^ (row & 7)) << 3);
}
// async 16B global->LDS (linear dest; swizzle lives in the SOURCE layout)
__device__ inline void gl16(const unsigned short* g, unsigned short* l) {
    __builtin_amdgcn_global_load_lds(
        (const __attribute__((address_space(1))) void*)g,
        (__attribute__((address_space(3))) void*)l, 16, 0, 0);
}
// pre-swizzled h destination offset for (node, lane) -> lane's 4 cols
__device__ inline int hdst(int node, int lane) {
    return ((lane >> 4) << 6) + (((((lane >> 1) & 7)) ^ (node & 7)) << 3)
         + ((lane & 1) << 2);
}

// ---------------------------------------------------------------------------
// prep: [blocks 0..1023] W [K][N] f32 -> Wt [N][K] bf16 PRE-SWIZZLED
//       [blocks 1024..2047] xb = bf16(x)
//       [blocks 2048..] dst-degree histogram for both edge sets
// ---------------------------------------------------------------------------
__global__ __launch_bounds__(256) void prep_kernel(
    const float* __restrict__ W1d, const float* __restrict__ W2d,
    const float* __restrict__ W1u, const float* __restrict__ W2u,
    unsigned short* __restrict__ Wt,
    const float* __restrict__ x, unsigned short* __restrict__ xb,
    const int* __restrict__ ei, const int* __restrict__ vi,
    int* __restrict__ degD, int* __restrict__ degU)
{
    int b = blockIdx.x, t = threadIdx.x;
    if (b < PREP_W_BLOCKS) {
        int w = b >> 8, n = b & 255;
        const float* W = (w == 0) ? W1d : (w == 1) ? W2d : (w == 2) ? W1u : W2u;
        int k0 = (t >> 6) << 6, kg = (t >> 3) & 7, j = t & 7;
        int src = k0 + ((kg ^ (n & 7)) << 3) + j;     // inverse-XOR source col
        Wt[(size_t)w * DIM * DIM + (size_t)n * DIM + t] =
            f2bf(W[(size_t)src * DIM + n]);
    } else if (b < PREP_W_BLOCKS + PREP_X_BLOCKS) {
        int idx = (b - PREP_W_BLOCKS) * 256 + t;
        const int stride = PREP_X_BLOCKS * 256;
        const int total = N_NODES * (DIM / 8);
        for (int f = idx; f < total; f += stride) {
            float4 v0 = ((const float4*)x)[f * 2];
            float4 v1 = ((const float4*)x)[f * 2 + 1];
            s16x8 pk;
            pk[0] = f2bf(v0.x); pk[1] = f2bf(v0.y);
            pk[2] = f2bf(v0.z); pk[3] = f2bf(v0.w);
            pk[4] = f2bf(v1.x); pk[5] = f2bf(v1.y);
            pk[6] = f2bf(v1.z); pk[7] = f2bf(v1.w);
            *(s16x8*)(xb + (size_t)f * 8) = pk;
        }
    } else {
        int i = (b - PREP_W_BLOCKS - PREP_X_BLOCKS) * 256 + t;
        if (i < NE) atomicAdd(&degD[ei[NE + i]], 1);
        else if (i < NE + NEV) { int j2 = i - NE; atomicAdd(&degU[vi[NEV + j2]], 1); }
    }
}

// ---------------------------------------------------------------------------
// CSR scan + fill (packs (e,src) int2)
// ---------------------------------------------------------------------------
__global__ __launch_bounds__(1024) void scan2_kernel(
    int* __restrict__ offD, int* __restrict__ curD,
    int* __restrict__ offU, int* __restrict__ curU)
{
    int* deg_offsets = (blockIdx.x == 0) ? offD : offU;
    int* cursor      = (blockIdx.x == 0) ? curD : curU;
    int E            = (blockIdx.x == 0) ? NE : NEV;
    __shared__ int part[1024];
    int t = threadIdx.x;
    const int CH = (N_NODES + 1023) / 1024;
    int beg = t * CH;
    int end = min(beg + CH, N_NODES);
    int s = 0;
    for (int i = beg; i < end; i++) s += deg_offsets[i];
    part[t] = s;
    __syncthreads();
    for (int off = 1; off < 1024; off <<= 1) {
        int v = part[t];
        int u = (t >= off) ? part[t - off] : 0;
        __syncthreads();
        part[t] = v + u;
        __syncthreads();
    }
    int run = (t > 0) ? part[t - 1] : 0;
    for (int i = beg; i < end; i++) {
        int dv = deg_offsets[i];
        deg_offsets[i] = run;
        cursor[i] = run;
        run += dv;
    }
    if (t == 1023) deg_offsets[N_NODES] = E;
}

__global__ __launch_bounds__(256) void fill2_kernel(
    const int* __restrict__ ei, const int* __restrict__ vi,
    int* __restrict__ curD, int* __restrict__ curU,
    int2* __restrict__ pairsD, int2* __restrict__ pairsU)
{
    int i = blockIdx.x * blockDim.x + threadIdx.x;
    if (i < NE) {
        int s = ei[i], d = ei[NE + i];
        int pos = atomicAdd(&curD[d], 1);
        pairsD[pos] = make_int2(i, s);
    } else if (i < NE + NEV) {
        int j = i - NE;
        int s = vi[j], d = vi[NEV + j];
        int pos = atomicAdd(&curU[d], 1);
        pairsU[pos] = make_int2(j, s);
    }
}

// ---------------------------------------------------------------------------
// gather: TWO waves per node (even/odd edge split), 4 edges in flight per
// wave; x rows read as bf16 (xb); emits h PRE-SWIZZLED for gemm1 gl16.
// ---------------------------------------------------------------------------
__device__ inline f32x4 ldnt4(const float* p) {
    return __builtin_nontemporal_load((const f32x4*)p);
}
__device__ inline f32x4 bf4f(ushort4 v) {
    f32x4 r;
    r.x = bf2f(v.x); r.y = bf2f(v.y); r.z = bf2f(v.z); r.w = bf2f(v.w);
    return r;
}
__device__ inline void acc_relu(f32x4& acc, f32x4 a, f32x4 b) {
    acc.x += fmaxf(a.x + b.x, 0.f);
    acc.y += fmaxf(a.y + b.y, 0.f);
    acc.z += fmaxf(a.z + b.z, 0.f);
    acc.w += fmaxf(a.w + b.w, 0.f);
}

__global__ __launch_bounds__(256) void gather2_kernel(
    const unsigned short* __restrict__ xb, const float* __restrict__ ea,
    const float* __restrict__ vea,
    const int* __restrict__ offD, const int2* __restrict__ pairsD,
    const int* __restrict__ offU, const int2* __restrict__ pairsU,
    const float* __restrict__ epsd, const float* __restrict__ epsu,
    unsigned short* __restrict__ hD, unsigned short* __restrict__ hU)
{
    __shared__ f32x4 part[2][64];
    int warp = threadIdx.x >> 6;
    int lane = threadIdx.x & 63;
    int slotn = warp >> 1;
    int half = warp & 1;
    int nidx = blockIdx.x * 2 + slotn;
    bool down = nidx < N_NODES;
    int node = down ? nidx : nidx - N_NODES;
    const int* off      = down ? offD   : offU;
    const int2* pairs   = down ? pairsD : pairsU;
    const float* eat    = down ? ea     : vea;
    unsigned short* h   = down ? hD     : hU;
    float epsv = 1.0f + (down ? epsd[0] : epsu[0]);

    int beg = off[node], end = off[node + 1];
    f32x4 acc = {0.f, 0.f, 0.f, 0.f};
    int cofs = lane * 4;
    int p = beg + half;
    // 4 edges in flight (stride-2 parity stream): 8 independent loads issued
    for (; p + 6 < end; p += 8) {
        int2 q0 = pairs[p],     q1 = pairs[p + 2];
        int2 q2 = pairs[p + 4], q3 = pairs[p + 6];
        ushort4 a0 = *(const ushort4*)(xb + (size_t)q0.y * DIM + cofs);
        f32x4 b0 = ldnt4(eat + (size_t)q0.x * DIM + cofs);
        ushort4 a1 = *(const ushort4*)(xb + (size_t)q1.y * DIM + cofs);
        f32x4 b1 = ldnt4(eat + (size_t)q1.x * DIM + cofs);
        ushort4 a2 = *(const ushort4*)(xb + (size_t)q2.y * DIM + cofs);
        f32x4 b2 = ldnt4(eat + (size_t)q2.x * DIM + cofs);
        ushort4 a3 = *(const ushort4*)(xb + (size_t)q3.y * DIM + cofs);
        f32x4 b3 = ldnt4(eat + (size_t)q3.x * DIM + cofs);
        acc_relu(acc, bf4f(a0), b0);
        acc_relu(acc, bf4f(a1), b1);
        acc_relu(acc, bf4f(a2), b2);
        acc_relu(acc, bf4f(a3), b3);
    }
    for (; p + 2 < end; p += 4) {
        int2 q0 = pairs[p], q1 = pairs[p + 2];
        ushort4 a0 = *(const ushort4*)(xb + (size_t)q0.y * DIM + cofs);
        f32x4 b0 = ldnt4(eat + (size_t)q0.x * DIM + cofs);
        ushort4 a1 = *(const ushort4*)(xb + (size_t)q1.y * DIM + cofs);
        f32x4 b1 = ldnt4(eat + (size_t)q1.x * DIM + cofs);
        acc_relu(acc, bf4f(a0), b0);
        acc_relu(acc, bf4f(a1), b1);
    }
    if (p < end) {
        int2 q0 = pairs[p];
        ushort4 a0 = *(const ushort4*)(xb + (size_t)q0.y * DIM + cofs);
        f32x4 b0 = ldnt4(eat + (size_t)q0.x * DIM + cofs);
        acc_relu(acc, bf4f(a0), b0);
    }
    if (half == 1) part[slotn][lane] = acc;
    __syncthreads();
    if (half == 0) {
        f32x4 o = part[slotn][lane];
        acc.x += o.x; acc.y += o.y; acc.z += o.z; acc.w += o.w;
        f32x4 xv = bf4f(*(const ushort4*)(xb + (size_t)node * DIM + cofs));
        acc.x = fmaf(epsv, xv.x, acc.x);
        acc.y = fmaf(epsv, xv.y, acc.y);
        acc.z = fmaf(epsv, xv.z, acc.z);
        acc.w = fmaf(epsv, xv.w, acc.w);
        ushort4 pk;
        pk.x = f2bf(acc.x); pk.y = f2bf(acc.y);
        pk.z = f2bf(acc.z); pk.w = f2bf(acc.w);
        *(ushort4*)(h + (size_t)node * DIM + hdst(node, lane)) = pk;
    }
}

// ---------------------------------------------------------------------------
// FALLBACK: atomic scatter into f32 aggr + convert (pre-swizzled h out)
// ---------------------------------------------------------------------------
__global__ __launch_bounds__(256) void scatter_kernel(
    const float* __restrict__ x, const float* __restrict__ ea,
    const int* __restrict__ idx, int E, float* __restrict__ buf)
{
    int wid = blockIdx.x * (blockDim.x >> 6) + (threadIdx.x >> 6);
    int lane = threadIdx.x & 63;
    if (wid >= E) return;
    int s = idx[wid];
    int d = idx[E + wid];
    float4 a = ((const float4*)(x + (size_t)s * DIM))[lane];
    float4 b = ((const float4*)(ea + (size_t)wid * DIM))[lane];
    float* dst = buf + (size_t)d * DIM + lane * 4;
    atomicAdd(dst + 0, fmaxf(a.x + b.x, 0.f));
    atomicAdd(dst + 1, fmaxf(a.y + b.y, 0.f));
    atomicAdd(dst + 2, fmaxf(a.z + b.z, 0.f));
    atomicAdd(dst + 3, fmaxf(a.w + b.w, 0.f));
}

__global__ __launch_bounds__(256) void conv_kernel(
    const float* __restrict__ x, const float* __restrict__ aggr,
    const float* __restrict__ eps_p, unsigned short* __restrict__ h)
{
    float epsv = 1.0f + eps_p[0];
    int i = blockIdx.x * blockDim.x + threadIdx.x;
    const int total = N_NODES * 64;
    for (int f = i; f < total; f += gridDim.x * blockDim.x) {
        int node = f >> 6, lane = f & 63;
        size_t o = (size_t)node * DIM + lane * 4;
        float4 xv = *(const float4*)(x + o);
        float4 av = *(const float4*)(aggr + o);
        ushort4 pk;
        pk.x = f2bf(fmaf(epsv, xv.x, av.x));
        pk.y = f2bf(fmaf(epsv, xv.y, av.y));
        pk.z = f2bf(fmaf(epsv, xv.z, av.z));
        pk.w = f2bf(fmaf(epsv, xv.w, av.w));
        *(ushort4*)(h + (size_t)node * DIM + hdst(node, lane)) = pk;
    }
}

// ---------------------------------------------------------------------------
// MFMA GEMM stage 1 (BOTH paths): A and B staged via global_load_lds
// (linear LDS dest; h and Wt are pre-swizzled in global memory).
// ---------------------------------------------------------------------------
__global__ __launch_bounds__(256) void gemm1_both(
    const unsigned short* __restrict__ hD, const unsigned short* __restrict__ hU,
    const unsigned short* __restrict__ Wt1d, const unsigned short* __restrict__ Wt1u,
    const float* __restrict__ b1d, const float* __restrict__ b1u,
    unsigned short* __restrict__ t1D, unsigned short* __restrict__ t1U,
    float* __restrict__ sumD, float* __restrict__ sqD,
    float* __restrict__ sumU, float* __restrict__ sqU)
{
    __shared__ unsigned short As[BM * BK];
    __shared__ unsigned short Bs[DIM * BK];
    int blk = blockIdx.x;
    bool down = blk < GRID_PER;
    int bb = down ? blk : blk - GRID_PER;
    const unsigned short* h  = down ? hD   : hU;
    const unsigned short* Wt = down ? Wt1d : Wt1u;
    const float* bias        = down ? b1d  : b1u;
    unsigned short* t1       = down ? t1D  : t1U;
    float* ssum              = down ? sumD : sumU;
    float* ssq               = down ? sqD  : sqU;

    int t = threadIdx.x;
    int w = t >> 6, l = t & 63, lrow = l & 15, kgrp = l >> 4;
    int row0 = bb * BM;

    f32x4 acc[16];
    #pragma unroll
    for (int i = 0; i < 16; ++i) acc[i] = (f32x4){0.f, 0.f, 0.f, 0.f};

    for (int k0 = 0; k0 < DIM; k0 += BK) {
        __syncthreads();
        #pragma unroll
        for (int it = 0; it < 2; ++it) {
            int g = it * 256 + t;
            gl16(h + (size_t)(row0 + (g >> 3)) * DIM + k0 + ((g & 7) << 3),
                 &As[g << 3]);
        }
        #pragma unroll
        for (int it = 0; it < 8; ++it) {
            int g = it * 256 + t;
            gl16(Wt + (size_t)(g >> 3) * DIM + k0 + ((g & 7) << 3),
                 &Bs[g << 3]);
        }
        __syncthreads();
        #pragma unroll
        for (int kk = 0; kk < 2; ++kk) {
            s16x8 af[4], bf[4];
            #pragma unroll
            for (int mi = 0; mi < 4; ++mi)
                af[mi] = *(const s16x8*)&As[swz(mi * 16 + lrow, kk * 4 + kgrp)];
            #pragma unroll
            for (int ni = 0; ni < 4; ++ni)
                bf[ni] = *(const s16x8*)&Bs[swz(w * 64 + ni * 16 + lrow, kk * 4 + kgrp)];
            #pragma unroll
            for (int mi = 0; mi < 4; ++mi)
                #pragma unroll
                for (int ni = 0; ni < 4; ++ni)
                    acc[mi * 4 + ni] = __builtin_amdgcn_mfma_f32_16x16x32_bf16(
                        af[mi], bf[ni], acc[mi * 4 + ni], 0, 0, 0);
        }
    }
    int slot = bb & (NSLOT - 1);
    #pragma unroll
    for (int ni = 0; ni < 4; ++ni) {
        int col = w * 64 + ni * 16 + lrow;
        float bv = bias[col];
        float s = 0.f, q = 0.f;
        #pragma unroll
        for (int mi = 0; mi < 4; ++mi) {
            #pragma unroll
            for (int r = 0; r < 4; ++r) {
                int grow = row0 + mi * 16 + kgrp * 4 + r;
                if (grow < N_NODES) {
                    float v = acc[mi * 4 + ni][r] + bv;
                    t1[(size_t)grow * DIM + col] = f2bf(v);
                    s += v; q += v * v;
                }
            }
        }
        s += __shfl_xor(s, 16); q += __shfl_xor(q, 16);
        s += __shfl_xor(s, 32); q += __shfl_xor(q, 32);
        if (kgrp == 0) {
            atomicAdd(&ssum[slot * DIM + col], s);
            atomicAdd(&ssq[slot * DIM + col], q);
        }
    }
}

// ---------------------------------------------------------------------------
// per-column BN params from NSLOT-sliced stats
// ---------------------------------------------------------------------------
__device__ inline void bn_finalize(
    const float* ssum, const float* ssq, const float* g, const float* b,
    float* scale, float* shift, int c)
{
    float s = 0.f, q = 0.f;
    #pragma unroll
    for (int k = 0; k < NSLOT; ++k) { s += ssum[k * DIM + c]; q += ssq[k * DIM + c]; }
    const float invN = 1.0f / (float)N_NODES;
    float mu = s * invN;
    float var = q * invN - mu * mu;
    float sc = g[c] * rsqrtf(var + 1e-5f);
    scale[c] = sc;
    shift[c] = b[c] - mu * sc;
}

// ---------------------------------------------------------------------------
// FUSED stage 2: BN1(LDS) -> GEMM D -> GEMM U -> out = x + C1 + C2 + stats.
// A reg-staged (BN work) with write-side XOR; B via gl16 (pre-swizzled Wt2).
// ---------------------------------------------------------------------------
__global__ __launch_bounds__(256) void gemm2_fused(
    const unsigned short* __restrict__ t1D, const unsigned short* __restrict__ t1U,
    const float* __restrict__ sumD, const float* __restrict__ sqD,
    const float* __restrict__ g1d, const float* __restrict__ bt1d,
    const float* __restrict__ sumU, const float* __restrict__ sqU,
    const float* __restrict__ g1u, const float* __restrict__ bt1u,
    const unsigned short* __restrict__ Wt2d, const unsigned short* __restrict__ Wt2u,
    const float* __restrict__ b2d, const float* __restrict__ b2u,
    const float* __restrict__ a1, const float* __restrict__ a2,
    const float* __restrict__ x, float* __restrict__ out,
    float* __restrict__ sumF, float* __restrict__ sqF)
{
    __shared__ unsigned short As[BM * BK];
    __shared__ unsigned short Bs[DIM * BK];
    __shared__ float scDl[DIM], shDl[DIM], scUl[DIM], shUl[DIM];
    int t = threadIdx.x;
    int w = t >> 6, l = t & 63, lrow = l & 15, kgrp = l >> 4;
    int bb = blockIdx.x;
    int row0 = bb * BM;

    bn_finalize(sumD, sqD, g1d, bt1d, scDl, shDl, t);
    bn_finalize(sumU, sqU, g1u, bt1u, scUl, shUl, t);
    float a1v = a1[0], a2v = a2[0];

    f32x4 acc[16], accO[16];
    #pragma unroll
    for (int i = 0; i < 16; ++i) acc[i] = (f32x4){0.f, 0.f, 0.f, 0.f};

    #pragma unroll
    for (int phase = 0; phase < 2; ++phase) {
        const unsigned short* t1 = phase == 0 ? t1D : t1U;
        const unsigned short* Wt = phase == 0 ? Wt2d : Wt2u;
        const float* scl = phase == 0 ? scDl : scUl;
        const float* shl = phase == 0 ? shDl : shUl;
        for (int k0 = 0; k0 < DIM; k0 += BK) {
            __syncthreads();
            #pragma unroll
            for (int it = 0; it < 8; ++it) {
                int g = it * 256 + t;
                gl16(Wt + (size_t)(g >> 3) * DIM + k0 + ((g & 7) << 3),
                     &Bs[g << 3]);
            }
            #pragma unroll
            for (int it = 0; it < 2; ++it) {
                int g = it * 256 + t, row = g >> 3, kg = g & 7;
                int gr = row0 + row;
                s16x8 pack = {0, 0, 0, 0, 0, 0, 0, 0};
                if (gr < N_NODES) {
                    s16x8 tv = *(const s16x8*)(t1 + (size_t)gr * DIM + k0 + kg * 8);
                    #pragma unroll
                    for (int j = 0; j < 8; ++j) {
                        int c = k0 + kg * 8 + j;
                        pack[j] = f2bf(fmaxf(fmaf(bf2f((unsigned short)tv[j]), scl[c], shl[c]), 0.f));
                    }
                }
                *(s16x8*)&As[swz(row, kg)] = pack;
            }
            __syncthreads();
            #pragma unroll
            for (int kk = 0; kk < 2; ++kk) {
                s16x8 af[4], bf[4];
                #pragma unroll
                for (int mi = 0; mi < 4; ++mi)
                    af[mi] = *(const s16x8*)&As[swz(mi * 16 + lrow, kk * 4 + kgrp)];
                #pragma unroll
                for (int ni = 0; ni < 4; ++ni)
                    bf[ni] = *(const s16x8*)&Bs[swz(w * 64 + ni * 16 + lrow, kk * 4 + kgrp)];
                #pragma unroll
                for (int mi = 0; mi < 4; ++mi)
                    #pragma unroll
                    for (int ni = 0; ni < 4; ++ni)
                        acc[mi * 4 + ni] = __builtin_amdgcn_mfma_f32_16x16x32_bf16(
                            af[mi], bf[ni], acc[mi * 4 + ni], 0, 0, 0);
            }
        }
        if (phase == 0) {
            #pragma unroll
            for (int ni = 0; ni < 4; ++ni) {
                float bv = b2d[w * 64 + ni * 16 + lrow];
                #pragma unroll
                for (int mi = 0; mi < 4; ++mi) {
                    #pragma unroll
                    for (int r = 0; r < 4; ++r)
                        accO[mi * 4 + ni][r] = a1v * (acc[mi * 4 + ni][r] + bv);
                    acc[mi * 4 + ni] = (f32x4){0.f, 0.f, 0.f, 0.f};
                }
            }
        }
    }

    int slot = bb & (NSLOT - 1);
    #pragma unroll
    for (int ni = 0; ni < 4; ++ni) {
        int col = w * 64 + ni * 16 + lrow;
        float bvU = b2u[col];
        float s = 0.f, q = 0.f;
        #pragma unroll
        for (int mi = 0; mi < 4; ++mi) {
            #pragma unroll
            for (int r = 0; r < 4; ++r) {
                int grow = row0 + mi * 16 + kgrp * 4 + r;
                if (grow < N_NODES) {
                    size_t o = (size_t)grow * DIM + col;
                    float v = x[o] + accO[mi * 4 + ni][r]
                            + a2v * (acc[mi * 4 + ni][r] + bvU);
                    out[o] = v;
                    s += v; q += v * v;
                }
            }
        }
        s += __shfl_xor(s, 16); q += __shfl_xor(q, 16);
        s += __shfl_xor(s, 32); q += __shfl_xor(q, 32);
        if (kgrp == 0) {
            atomicAdd(&sumF[slot * DIM + col], s);
            atomicAdd(&sqF[slot * DIM + col], q);
        }
    }
}

// ---------------------------------------------------------------------------
// final BN + ReLU with fused finalize
// ---------------------------------------------------------------------------
__global__ __launch_bounds__(256) void bnrelu_kernel(
    float* __restrict__ out,
    const float* __restrict__ sumF, const float* __restrict__ sqF,
    const float* __restrict__ bng, const float* __restrict__ bnb)
{
    __shared__ float scl[DIM], shl[DIM];
    bn_finalize(sumF, sqF, bng, bnb, scl, shl, threadIdx.x);
    __syncthreads();
    int idx = blockIdx.x * blockDim.x + threadIdx.x;
    const int total = N_NODES * (DIM / 4);
    for (int f = idx; f < total; f += gridDim.x * blockDim.x) {
        float4 v = ((float4*)out)[f];
        int c = (f * 4) & (DIM - 1);
        float4 sc = *(const float4*)(scl + c);
        float4 sh = *(const float4*)(shl + c);
        v.x = fmaxf(v.x * sc.x + sh.x, 0.0f);
        v.y = fmaxf(v.y * sc.y + sh.y, 0.0f);
        v.z = fmaxf(v.z * sc.z + sh.z, 0.0f);
        v.w = fmaxf(v.w * sc.w + sh.w, 0.0f);
        ((float4*)out)[f] = v;
    }
}

extern "C" void kernel_launch(void* const* d_in, const int* in_sizes, int n_in,
                              void* d_out, int out_size, void* d_ws, size_t ws_size,
                              hipStream_t stream)
{
    const float* x    = (const float*)d_in[0];
    const int*   ei   = (const int*)  d_in[1];
    const float* ea   = (const float*)d_in[2];
    const int*   vi   = (const int*)  d_in[3];
    const float* vea  = (const float*)d_in[4];
    const float* epsd = (const float*)d_in[5];
    const float* W1d  = (const float*)d_in[6];
    const float* b1d  = (const float*)d_in[7];
    const float* g1d  = (const float*)d_in[8];
    const float* bt1d = (const float*)d_in[9];
    const float* W2d  = (const float*)d_in[10];
    const float* b2d  = (const float*)d_in[11];
    const float* epsu = (const float*)d_in[12];
    const float* W1u  = (const float*)d_in[13];
    const float* b1u  = (const float*)d_in[14];
    const float* g1u  = (const float*)d_in[15];
    const float* bt1u = (const float*)d_in[16];
    const float* W2u  = (const float*)d_in[17];
    const float* b2u  = (const float*)d_in[18];
    const float* bng  = (const float*)d_in[19];
    const float* bnb  = (const float*)d_in[20];
    const float* a1   = (const float*)d_in[21];
    const float* a2   = (const float*)d_in[22];

    float* out = (float*)d_out;

    // ---- workspace layout ----
    char* p = (char*)d_ws;
    unsigned short* hD  = (unsigned short*)p;  p += (size_t)N_NODES * DIM * 2;
    unsigned short* hU  = (unsigned short*)p;  p += (size_t)N_NODES * DIM * 2;
    unsigned short* t1D = (unsigned short*)p;  p += (size_t)N_NODES * DIM * 2;
    unsigned short* t1U = (unsigned short*)p;  p += (size_t)N_NODES * DIM * 2;
    unsigned short* xb  = (unsigned short*)p;  p += (size_t)N_NODES * DIM * 2;
    unsigned short* Wt  = (unsigned short*)p;  p += (size_t)4 * DIM * DIM * 2;
    // zeroed region: stats (6 slices) + offsets
    char* zero_base = p;
    float* stats = (float*)p;                  p += (size_t)6 * NSLOT * DIM * 4;
    int* offD = (int*)p;                       p += (size_t)(N_NODES + 1) * 4;
    int* offU = (int*)p;                       p += (size_t)(N_NODES + 1) * 4;
    size_t zero_bytes = (size_t)(p - zero_base);
    int* curD = (int*)p;                       p += (size_t)N_NODES * 4;
    int* curU = (int*)p;                       p += (size_t)N_NODES * 4;
    char* union_base = p;
    int2* pairsD = (int2*)p;                   p += (size_t)NE * 8;
    int2* pairsU = (int2*)p;                   p += (size_t)NEV * 8;
    size_t need_csr = (size_t)(p - (char*)d_ws);
    float* aggr = (float*)union_base;          // fallback-only, overlaps pairs
    size_t need_fb = (size_t)(union_base - (char*)d_ws) + (size_t)N_NODES * DIM * 4;
    bool use_csr = ws_size >= need_csr;

    float* sumD = stats;
    float* sqD  = stats + 1 * NSLOT * DIM;
    float* sumU = stats + 2 * NSLOT * DIM;
    float* sqU  = stats + 3 * NSLOT * DIM;
    float* sumF = stats + 4 * NSLOT * DIM;
    float* sqF  = stats + 5 * NSLOT * DIM;

    unsigned short* Wt1d = Wt;
    unsigned short* Wt2d = Wt + 1 * (size_t)DIM * DIM;
    unsigned short* Wt1u = Wt + 2 * (size_t)DIM * DIM;
    unsigned short* Wt2u = Wt + 3 * (size_t)DIM * DIM;

    hipMemsetAsync(zero_base, 0, zero_bytes, stream);

    if (use_csr) {
        prep_kernel<<<PREP_W_BLOCKS + PREP_X_BLOCKS + HIST_BLOCKS, 256, 0, stream>>>(
            W1d, W2d, W1u, W2u, Wt, x, xb, ei, vi, offD, offU);
        scan2_kernel<<<2, 1024, 0, stream>>>(offD, curD, offU, curU);
        fill2_kernel<<<(NE + NEV + 255) / 256, 256, 0, stream>>>(
            ei, vi, curD, curU, pairsD, pairsU);
        gather2_kernel<<<N_NODES, 256, 0, stream>>>(
            xb, ea, vea, offD, pairsD, offU, pairsU, epsd, epsu, hD, hU);
    } else if (ws_size >= need_fb) {
        prep_kernel<<<PREP_W_BLOCKS + PREP_X_BLOCKS, 256, 0, stream>>>(
            W1d, W2d, W1u, W2u, Wt, x, xb, ei, vi, offD, offU);
        hipMemsetAsync(aggr, 0, (size_t)N_NODES * DIM * 4, stream);
        scatter_kernel<<<(NE + 3) / 4, 256, 0, stream>>>(x, ea, ei, NE, aggr);
        conv_kernel<<<2048, 256, 0, stream>>>(x, aggr, epsd, hD);
        hipMemsetAsync(aggr, 0, (size_t)N_NODES * DIM * 4, stream);
        scatter_kernel<<<(NEV + 3) / 4, 256, 0, stream>>>(x, vea, vi, NEV, aggr);
        conv_kernel<<<2048, 256, 0, stream>>>(x, aggr, epsu, hU);
    }

    gemm1_both<<<2 * GRID_PER, 256, 0, stream>>>(
        hD, hU, Wt1d, Wt1u, b1d, b1u, t1D, t1U, sumD, sqD, sumU, sqU);

    gemm2_fused<<<GRID_PER, 256, 0, stream>>>(
        t1D, t1U, sumD, sqD, g1d, bt1d, sumU, sqU, g1u, bt1u,
        Wt2d, Wt2u, b2d, b2u, a1, a2, x, out, sumF, sqF);

    bnrelu_kernel<<<2048, 256, 0, stream>>>(out, sumF, sqF, bng, bnb);
}

// Round 12
// 412.443 us; speedup vs baseline: 1.0401x; 1.0004x over previous
//
#include <hip/hip_runtime.h>
#include <math.h>

#define N_NODES 50000
#define DIM 256
#define NE 300000
#define NEV 100000
#define BM 64
#define BK 64
#define NSLOT 8
#define GRID_PER ((N_NODES + BM - 1) / BM)   // 782
#define PREP_W_BLOCKS (4 * DIM)              // 1024
#define PREP_X_BLOCKS 1024
#define HIST_BLOCKS ((NE + NEV + 255) / 256) // 1563

typedef float f32x4 __attribute__((ext_vector_type(4)));
typedef short s16x8 __attribute__((ext_vector_type(8)));

__device__ inline unsigned short f2bf(float f) {
    unsigned u = __float_as_uint(f);
    u += 0x7FFF + ((u >> 16) & 1);            // round-to-nearest-even
    return (unsigned short)(u >> 16);
}
__device__ inline float bf2f(unsigned short s) {
    return __uint_as_float(((unsigned)s) << 16);
}
// swizzled halfword offset inside a [R][64] bf16 tile (16B granules, T2 XOR)
__device__ inline int swz(int row, int kg) {
    return row * BK + ((kg ^ (row & 7)) << 3);
}
// async 16B global->LDS (linear dest; swizzle lives in the SOURCE layout)
__device__ inline void gl16(const unsigned short* g, unsigned short* l) {
    __builtin_amdgcn_global_load_lds(
        (const __attribute__((address_space(1))) void*)g,
        (__attribute__((address_space(3))) void*)l, 16, 0, 0);
}
// pre-swizzled h destination offset for (node, lane) -> lane's 4 cols
__device__ inline int hdst(int node, int lane) {
    return ((lane >> 4) << 6) + (((((lane >> 1) & 7)) ^ (node & 7)) << 3)
         + ((lane & 1) << 2);
}

// ---------------------------------------------------------------------------
// prep: [blocks 0..1023] W [K][N] f32 -> Wt [N][K] bf16 PRE-SWIZZLED
//       [blocks 1024..2047] xb = bf16(x)
//       [blocks 2048..] dst-degree histogram for both edge sets
// ---------------------------------------------------------------------------
__global__ __launch_bounds__(256) void prep_kernel(
    const float* __restrict__ W1d, const float* __restrict__ W2d,
    const float* __restrict__ W1u, const float* __restrict__ W2u,
    unsigned short* __restrict__ Wt,
    const float* __restrict__ x, unsigned short* __restrict__ xb,
    const int* __restrict__ ei, const int* __restrict__ vi,
    int* __restrict__ degD, int* __restrict__ degU)
{
    int b = blockIdx.x, t = threadIdx.x;
    if (b < PREP_W_BLOCKS) {
        int w = b >> 8, n = b & 255;
        const float* W = (w == 0) ? W1d : (w == 1) ? W2d : (w == 2) ? W1u : W2u;
        int k0 = (t >> 6) << 6, kg = (t >> 3) & 7, j = t & 7;
        int src = k0 + ((kg ^ (n & 7)) << 3) + j;     // inverse-XOR source col
        Wt[(size_t)w * DIM * DIM + (size_t)n * DIM + t] =
            f2bf(W[(size_t)src * DIM + n]);
    } else if (b < PREP_W_BLOCKS + PREP_X_BLOCKS) {
        int idx = (b - PREP_W_BLOCKS) * 256 + t;
        const int stride = PREP_X_BLOCKS * 256;
        const int total = N_NODES * (DIM / 8);
        for (int f = idx; f < total; f += stride) {
            float4 v0 = ((const float4*)x)[f * 2];
            float4 v1 = ((const float4*)x)[f * 2 + 1];
            s16x8 pk;
            pk[0] = f2bf(v0.x); pk[1] = f2bf(v0.y);
            pk[2] = f2bf(v0.z); pk[3] = f2bf(v0.w);
            pk[4] = f2bf(v1.x); pk[5] = f2bf(v1.y);
            pk[6] = f2bf(v1.z); pk[7] = f2bf(v1.w);
            *(s16x8*)(xb + (size_t)f * 8) = pk;
        }
    } else {
        int i = (b - PREP_W_BLOCKS - PREP_X_BLOCKS) * 256 + t;
        if (i < NE) atomicAdd(&degD[ei[NE + i]], 1);
        else if (i < NE + NEV) { int j2 = i - NE; atomicAdd(&degU[vi[NEV + j2]], 1); }
    }
}

// ---------------------------------------------------------------------------
// CSR scan + fill (packs (e,src) int2)
// ---------------------------------------------------------------------------
__global__ __launch_bounds__(1024) void scan2_kernel(
    int* __restrict__ offD, int* __restrict__ curD,
    int* __restrict__ offU, int* __restrict__ curU)
{
    int* deg_offsets = (blockIdx.x == 0) ? offD : offU;
    int* cursor      = (blockIdx.x == 0) ? curD : curU;
    int E            = (blockIdx.x == 0) ? NE : NEV;
    __shared__ int part[1024];
    int t = threadIdx.x;
    const int CH = (N_NODES + 1023) / 1024;
    int beg = t * CH;
    int end = min(beg + CH, N_NODES);
    int s = 0;
    for (int i = beg; i < end; i++) s += deg_offsets[i];
    part[t] = s;
    __syncthreads();
    for (int off = 1; off < 1024; off <<= 1) {
        int v = part[t];
        int u = (t >= off) ? part[t - off] : 0;
        __syncthreads();
        part[t] = v + u;
        __syncthreads();
    }
    int run = (t > 0) ? part[t - 1] : 0;
    for (int i = beg; i < end; i++) {
        int dv = deg_offsets[i];
        deg_offsets[i] = run;
        cursor[i] = run;
        run += dv;
    }
    if (t == 1023) deg_offsets[N_NODES] = E;
}

__global__ __launch_bounds__(256) void fill2_kernel(
    const int* __restrict__ ei, const int* __restrict__ vi,
    int* __restrict__ curD, int* __restrict__ curU,
    int2* __restrict__ pairsD, int2* __restrict__ pairsU)
{
    int i = blockIdx.x * blockDim.x + threadIdx.x;
    if (i < NE) {
        int s = ei[i], d = ei[NE + i];
        int pos = atomicAdd(&curD[d], 1);
        pairsD[pos] = make_int2(i, s);
    } else if (i < NE + NEV) {
        int j = i - NE;
        int s = vi[j], d = vi[NEV + j];
        int pos = atomicAdd(&curU[d], 1);
        pairsU[pos] = make_int2(j, s);
    }
}

// ---------------------------------------------------------------------------
// gather: TWO waves per node (even/odd edge split), 4 edges in flight per
// wave; x rows read as bf16 (xb); emits h PRE-SWIZZLED for gemm1 gl16.
// ---------------------------------------------------------------------------
__device__ inline f32x4 ldnt4(const float* p) {
    return __builtin_nontemporal_load((const f32x4*)p);
}
__device__ inline f32x4 bf4f(ushort4 v) {
    f32x4 r;
    r.x = bf2f(v.x); r.y = bf2f(v.y); r.z = bf2f(v.z); r.w = bf2f(v.w);
    return r;
}
__device__ inline void acc_relu(f32x4& acc, f32x4 a, f32x4 b) {
    acc.x += fmaxf(a.x + b.x, 0.f);
    acc.y += fmaxf(a.y + b.y, 0.f);
    acc.z += fmaxf(a.z + b.z, 0.f);
    acc.w += fmaxf(a.w + b.w, 0.f);
}

__global__ __launch_bounds__(256) void gather2_kernel(
    const unsigned short* __restrict__ xb, const float* __restrict__ ea,
    const float* __restrict__ vea,
    const int* __restrict__ offD, const int2* __restrict__ pairsD,
    const int* __restrict__ offU, const int2* __restrict__ pairsU,
    const float* __restrict__ epsd, const float* __restrict__ epsu,
    unsigned short* __restrict__ hD, unsigned short* __restrict__ hU)
{
    __shared__ f32x4 part[2][64];
    int warp = threadIdx.x >> 6;
    int lane = threadIdx.x & 63;
    int slotn = warp >> 1;
    int half = warp & 1;
    int nidx = blockIdx.x * 2 + slotn;
    bool down = nidx < N_NODES;
    int node = down ? nidx : nidx - N_NODES;
    const int* off      = down ? offD   : offU;
    const int2* pairs   = down ? pairsD : pairsU;
    const float* eat    = down ? ea     : vea;
    unsigned short* h   = down ? hD     : hU;
    float epsv = 1.0f + (down ? epsd[0] : epsu[0]);

    int beg = off[node], end = off[node + 1];
    f32x4 acc = {0.f, 0.f, 0.f, 0.f};
    int cofs = lane * 4;
    int p = beg + half;
    // 4 edges in flight (stride-2 parity stream): 8 independent loads issued
    for (; p + 6 < end; p += 8) {
        int2 q0 = pairs[p],     q1 = pairs[p + 2];
        int2 q2 = pairs[p + 4], q3 = pairs[p + 6];
        ushort4 a0 = *(const ushort4*)(xb + (size_t)q0.y * DIM + cofs);
        f32x4 b0 = ldnt4(eat + (size_t)q0.x * DIM + cofs);
        ushort4 a1 = *(const ushort4*)(xb + (size_t)q1.y * DIM + cofs);
        f32x4 b1 = ldnt4(eat + (size_t)q1.x * DIM + cofs);
        ushort4 a2 = *(const ushort4*)(xb + (size_t)q2.y * DIM + cofs);
        f32x4 b2 = ldnt4(eat + (size_t)q2.x * DIM + cofs);
        ushort4 a3 = *(const ushort4*)(xb + (size_t)q3.y * DIM + cofs);
        f32x4 b3 = ldnt4(eat + (size_t)q3.x * DIM + cofs);
        acc_relu(acc, bf4f(a0), b0);
        acc_relu(acc, bf4f(a1), b1);
        acc_relu(acc, bf4f(a2), b2);
        acc_relu(acc, bf4f(a3), b3);
    }
    for (; p + 2 < end; p += 4) {
        int2 q0 = pairs[p], q1 = pairs[p + 2];
        ushort4 a0 = *(const ushort4*)(xb + (size_t)q0.y * DIM + cofs);
        f32x4 b0 = ldnt4(eat + (size_t)q0.x * DIM + cofs);
        ushort4 a1 = *(const ushort4*)(xb + (size_t)q1.y * DIM + cofs);
        f32x4 b1 = ldnt4(eat + (size_t)q1.x * DIM + cofs);
        acc_relu(acc, bf4f(a0), b0);
        acc_relu(acc, bf4f(a1), b1);
    }
    if (p < end) {
        int2 q0 = pairs[p];
        ushort4 a0 = *(const ushort4*)(xb + (size_t)q0.y * DIM + cofs);
        f32x4 b0 = ldnt4(eat + (size_t)q0.x * DIM + cofs);
        acc_relu(acc, bf4f(a0), b0);
    }
    if (half == 1) part[slotn][lane] = acc;
    __syncthreads();
    if (half == 0) {
        f32x4 o = part[slotn][lane];
        acc.x += o.x; acc.y += o.y; acc.z += o.z; acc.w += o.w;
        f32x4 xv = bf4f(*(const ushort4*)(xb + (size_t)node * DIM + cofs));
        acc.x = fmaf(epsv, xv.x, acc.x);
        acc.y = fmaf(epsv, xv.y, acc.y);
        acc.z = fmaf(epsv, xv.z, acc.z);
        acc.w = fmaf(epsv, xv.w, acc.w);
        ushort4 pk;
        pk.x = f2bf(acc.x); pk.y = f2bf(acc.y);
        pk.z = f2bf(acc.z); pk.w = f2bf(acc.w);
        *(ushort4*)(h + (size_t)node * DIM + hdst(node, lane)) = pk;
    }
}

// ---------------------------------------------------------------------------
// FALLBACK: atomic scatter into f32 aggr + convert (pre-swizzled h out)
// ---------------------------------------------------------------------------
__global__ __launch_bounds__(256) void scatter_kernel(
    const float* __restrict__ x, const float* __restrict__ ea,
    const int* __restrict__ idx, int E, float* __restrict__ buf)
{
    int wid = blockIdx.x * (blockDim.x >> 6) + (threadIdx.x >> 6);
    int lane = threadIdx.x & 63;
    if (wid >= E) return;
    int s = idx[wid];
    int d = idx[E + wid];
    float4 a = ((const float4*)(x + (size_t)s * DIM))[lane];
    float4 b = ((const float4*)(ea + (size_t)wid * DIM))[lane];
    float* dst = buf + (size_t)d * DIM + lane * 4;
    atomicAdd(dst + 0, fmaxf(a.x + b.x, 0.f));
    atomicAdd(dst + 1, fmaxf(a.y + b.y, 0.f));
    atomicAdd(dst + 2, fmaxf(a.z + b.z, 0.f));
    atomicAdd(dst + 3, fmaxf(a.w + b.w, 0.f));
}

__global__ __launch_bounds__(256) void conv_kernel(
    const float* __restrict__ x, const float* __restrict__ aggr,
    const float* __restrict__ eps_p, unsigned short* __restrict__ h)
{
    float epsv = 1.0f + eps_p[0];
    int i = blockIdx.x * blockDim.x + threadIdx.x;
    const int total = N_NODES * 64;
    for (int f = i; f < total; f += gridDim.x * blockDim.x) {
        int node = f >> 6, lane = f & 63;
        size_t o = (size_t)node * DIM + lane * 4;
        float4 xv = *(const float4*)(x + o);
        float4 av = *(const float4*)(aggr + o);
        ushort4 pk;
        pk.x = f2bf(fmaf(epsv, xv.x, av.x));
        pk.y = f2bf(fmaf(epsv, xv.y, av.y));
        pk.z = f2bf(fmaf(epsv, xv.z, av.z));
        pk.w = f2bf(fmaf(epsv, xv.w, av.w));
        *(ushort4*)(h + (size_t)node * DIM + hdst(node, lane)) = pk;
    }
}

// ---------------------------------------------------------------------------
// MFMA GEMM stage 1 (BOTH paths): A and B staged via global_load_lds.
// Epilogue: t1 tile staged in Bs (LDS) then stored with coalesced 16B writes.
// ---------------------------------------------------------------------------
__global__ __launch_bounds__(256) void gemm1_both(
    const unsigned short* __restrict__ hD, const unsigned short* __restrict__ hU,
    const unsigned short* __restrict__ Wt1d, const unsigned short* __restrict__ Wt1u,
    const float* __restrict__ b1d, const float* __restrict__ b1u,
    unsigned short* __restrict__ t1D, unsigned short* __restrict__ t1U,
    float* __restrict__ sumD, float* __restrict__ sqD,
    float* __restrict__ sumU, float* __restrict__ sqU)
{
    __shared__ unsigned short As[BM * BK];
    __shared__ unsigned short Bs[DIM * BK];      // also reused as [64][256] out-tile
    int blk = blockIdx.x;
    bool down = blk < GRID_PER;
    int bb = down ? blk : blk - GRID_PER;
    const unsigned short* h  = down ? hD   : hU;
    const unsigned short* Wt = down ? Wt1d : Wt1u;
    const float* bias        = down ? b1d  : b1u;
    unsigned short* t1       = down ? t1D  : t1U;
    float* ssum              = down ? sumD : sumU;
    float* ssq               = down ? sqD  : sqU;

    int t = threadIdx.x;
    int w = t >> 6, l = t & 63, lrow = l & 15, kgrp = l >> 4;
    int row0 = bb * BM;

    f32x4 acc[16];
    #pragma unroll
    for (int i = 0; i < 16; ++i) acc[i] = (f32x4){0.f, 0.f, 0.f, 0.f};

    for (int k0 = 0; k0 < DIM; k0 += BK) {
        __syncthreads();
        #pragma unroll
        for (int it = 0; it < 2; ++it) {
            int g = it * 256 + t;
            gl16(h + (size_t)(row0 + (g >> 3)) * DIM + k0 + ((g & 7) << 3),
                 &As[g << 3]);
        }
        #pragma unroll
        for (int it = 0; it < 8; ++it) {
            int g = it * 256 + t;
            gl16(Wt + (size_t)(g >> 3) * DIM + k0 + ((g & 7) << 3),
                 &Bs[g << 3]);
        }
        __syncthreads();
        #pragma unroll
        for (int kk = 0; kk < 2; ++kk) {
            s16x8 af[4], bf[4];
            #pragma unroll
            for (int mi = 0; mi < 4; ++mi)
                af[mi] = *(const s16x8*)&As[swz(mi * 16 + lrow, kk * 4 + kgrp)];
            #pragma unroll
            for (int ni = 0; ni < 4; ++ni)
                bf[ni] = *(const s16x8*)&Bs[swz(w * 64 + ni * 16 + lrow, kk * 4 + kgrp)];
            #pragma unroll
            for (int mi = 0; mi < 4; ++mi)
                #pragma unroll
                for (int ni = 0; ni < 4; ++ni)
                    acc[mi * 4 + ni] = __builtin_amdgcn_mfma_f32_16x16x32_bf16(
                        af[mi], bf[ni], acc[mi * 4 + ni], 0, 0, 0);
        }
    }
    // epilogue: stage bf16 tile in Bs, compute stats from regs
    __syncthreads();                      // protect Bs from in-flight K-loop reads
    int slot = bb & (NSLOT - 1);
    #pragma unroll
    for (int ni = 0; ni < 4; ++ni) {
        int col = w * 64 + ni * 16 + lrow;
        float bv = bias[col];
        float s = 0.f, q = 0.f;
        #pragma unroll
        for (int mi = 0; mi < 4; ++mi) {
            #pragma unroll
            for (int r = 0; r < 4; ++r) {
                int lr = mi * 16 + kgrp * 4 + r;
                float v = acc[mi * 4 + ni][r] + bv;
                Bs[lr * DIM + col] = f2bf(v);
                if (row0 + lr < N_NODES) { s += v; q += v * v; }
            }
        }
        s += __shfl_xor(s, 16); q += __shfl_xor(q, 16);
        s += __shfl_xor(s, 32); q += __shfl_xor(q, 32);
        if (kgrp == 0) {
            atomicAdd(&ssum[slot * DIM + col], s);
            atomicAdd(&ssq[slot * DIM + col], q);
        }
    }
    __syncthreads();
    // coalesced 16B stores: 8 per thread
    #pragma unroll
    for (int it = 0; it < 8; ++it) {
        int g = it * 256 + t;
        int row = g >> 5, qd = g & 31;
        int grow = row0 + row;
        if (grow < N_NODES)
            *(s16x8*)(t1 + (size_t)grow * DIM + qd * 8) = *(const s16x8*)&Bs[g * 8];
    }
}

// ---------------------------------------------------------------------------
// per-column BN params from NSLOT-sliced stats
// ---------------------------------------------------------------------------
__device__ inline void bn_finalize(
    const float* ssum, const float* ssq, const float* g, const float* b,
    float* scale, float* shift, int c)
{
    float s = 0.f, q = 0.f;
    #pragma unroll
    for (int k = 0; k < NSLOT; ++k) { s += ssum[k * DIM + c]; q += ssq[k * DIM + c]; }
    const float invN = 1.0f / (float)N_NODES;
    float mu = s * invN;
    float var = q * invN - mu * mu;
    float sc = g[c] * rsqrtf(var + 1e-5f);
    scale[c] = sc;
    shift[c] = b[c] - mu * sc;
}

// ---------------------------------------------------------------------------
// FUSED stage 2: BN1(LDS) -> GEMM D -> GEMM U -> out = x + C1 + C2 + stats.
// Epilogue: f32 half-tiles staged in Bs; coalesced f32x4 x-read/out-write;
// column-quad stats LDS-reduced (combine-kernel pattern).
// ---------------------------------------------------------------------------
__global__ __launch_bounds__(256) void gemm2_fused(
    const unsigned short* __restrict__ t1D, const unsigned short* __restrict__ t1U,
    const float* __restrict__ sumD, const float* __restrict__ sqD,
    const float* __restrict__ g1d, const float* __restrict__ bt1d,
    const float* __restrict__ sumU, const float* __restrict__ sqU,
    const float* __restrict__ g1u, const float* __restrict__ bt1u,
    const unsigned short* __restrict__ Wt2d, const unsigned short* __restrict__ Wt2u,
    const float* __restrict__ b2d, const float* __restrict__ b2u,
    const float* __restrict__ a1, const float* __restrict__ a2,
    const float* __restrict__ x, float* __restrict__ out,
    float* __restrict__ sumF, float* __restrict__ sqF)
{
    __shared__ unsigned short As[BM * BK];       // 8KB; reused for stats reduce
    __shared__ unsigned short Bs[DIM * BK];      // 32KB; reused as f32 [32][256]
    __shared__ float scDl[DIM], shDl[DIM], scUl[DIM], shUl[DIM];
    int t = threadIdx.x;
    int w = t >> 6, l = t & 63, lrow = l & 15, kgrp = l >> 4;
    int bb = blockIdx.x;
    int row0 = bb * BM;

    bn_finalize(sumD, sqD, g1d, bt1d, scDl, shDl, t);
    bn_finalize(sumU, sqU, g1u, bt1u, scUl, shUl, t);
    float a1v = a1[0], a2v = a2[0];

    f32x4 acc[16], accO[16];
    #pragma unroll
    for (int i = 0; i < 16; ++i) acc[i] = (f32x4){0.f, 0.f, 0.f, 0.f};

    #pragma unroll
    for (int phase = 0; phase < 2; ++phase) {
        const unsigned short* t1 = phase == 0 ? t1D : t1U;
        const unsigned short* Wt = phase == 0 ? Wt2d : Wt2u;
        const float* scl = phase == 0 ? scDl : scUl;
        const float* shl = phase == 0 ? shDl : shUl;
        for (int k0 = 0; k0 < DIM; k0 += BK) {
            __syncthreads();
            #pragma unroll
            for (int it = 0; it < 8; ++it) {
                int g = it * 256 + t;
                gl16(Wt + (size_t)(g >> 3) * DIM + k0 + ((g & 7) << 3),
                     &Bs[g << 3]);
            }
            #pragma unroll
            for (int it = 0; it < 2; ++it) {
                int g = it * 256 + t, row = g >> 3, kg = g & 7;
                int gr = row0 + row;
                s16x8 pack = {0, 0, 0, 0, 0, 0, 0, 0};
                if (gr < N_NODES) {
                    s16x8 tv = *(const s16x8*)(t1 + (size_t)gr * DIM + k0 + kg * 8);
                    #pragma unroll
                    for (int j = 0; j < 8; ++j) {
                        int c = k0 + kg * 8 + j;
                        pack[j] = f2bf(fmaxf(fmaf(bf2f((unsigned short)tv[j]), scl[c], shl[c]), 0.f));
                    }
                }
                *(s16x8*)&As[swz(row, kg)] = pack;
            }
            __syncthreads();
            #pragma unroll
            for (int kk = 0; kk < 2; ++kk) {
                s16x8 af[4], bf[4];
                #pragma unroll
                for (int mi = 0; mi < 4; ++mi)
                    af[mi] = *(const s16x8*)&As[swz(mi * 16 + lrow, kk * 4 + kgrp)];
                #pragma unroll
                for (int ni = 0; ni < 4; ++ni)
                    bf[ni] = *(const s16x8*)&Bs[swz(w * 64 + ni * 16 + lrow, kk * 4 + kgrp)];
                #pragma unroll
                for (int mi = 0; mi < 4; ++mi)
                    #pragma unroll
                    for (int ni = 0; ni < 4; ++ni)
                        acc[mi * 4 + ni] = __builtin_amdgcn_mfma_f32_16x16x32_bf16(
                            af[mi], bf[ni], acc[mi * 4 + ni], 0, 0, 0);
            }
        }
        if (phase == 0) {
            #pragma unroll
            for (int ni = 0; ni < 4; ++ni) {
                float bv = b2d[w * 64 + ni * 16 + lrow];
                #pragma unroll
                for (int mi = 0; mi < 4; ++mi) {
                    #pragma unroll
                    for (int r = 0; r < 4; ++r)
                        accO[mi * 4 + ni][r] = a1v * (acc[mi * 4 + ni][r] + bv);
                    acc[mi * 4 + ni] = (f32x4){0.f, 0.f, 0.f, 0.f};
                }
            }
        }
    }

    // ---- epilogue: two 32-row half-passes through Bs (f32), coalesced IO ----
    float* Fs = (float*)Bs;                       // [32][256] f32
    f32x4 s4 = {0.f, 0.f, 0.f, 0.f}, q4 = {0.f, 0.f, 0.f, 0.f};
    #pragma unroll
    for (int half = 0; half < 2; ++half) {
        __syncthreads();                          // protect Bs
        #pragma unroll
        for (int ni = 0; ni < 4; ++ni) {
            int col = w * 64 + ni * 16 + lrow;
            float bvU = b2u[col];
            #pragma unroll
            for (int mi2 = 0; mi2 < 2; ++mi2) {
                int mi = half * 2 + mi2;
                #pragma unroll
                for (int r = 0; r < 4; ++r) {
                    int lr = mi2 * 16 + kgrp * 4 + r;      // local row in half
                    Fs[lr * DIM + col] = accO[mi * 4 + ni][r]
                                       + a2v * (acc[mi * 4 + ni][r] + bvU);
                }
            }
        }
        __syncthreads();
        #pragma unroll
        for (int it = 0; it < 8; ++it) {
            int g = it * 256 + t;
            int row = g >> 6;                     // 0..31
            int grow = row0 + half * 32 + row;
            if (grow < N_NODES) {
                size_t o = (size_t)grow * DIM + (g & 63) * 4;
                f32x4 xv = *(const f32x4*)(x + o);
                f32x4 v = xv + *(const f32x4*)&Fs[g * 4];
                *(f32x4*)(out + o) = v;
                s4 += v; q4 += v * v;
            }
        }
    }
    // stats reduce: thread owns column-quad (t&63); 4 row-groups to merge
    __syncthreads();
    f32x4* red = (f32x4*)As;                      // 512 slots of 16B = 8KB
    int rg = t >> 6, cq = t & 63;
    red[rg * 64 + cq] = s4;
    red[256 + rg * 64 + cq] = q4;
    __syncthreads();
    if (rg == 0) {
        f32x4 S = red[cq] + red[64 + cq] + red[128 + cq] + red[192 + cq];
        f32x4 Q = red[256 + cq] + red[320 + cq] + red[384 + cq] + red[448 + cq];
        int slot = bb & (NSLOT - 1);
        int c = cq * 4;
        atomicAdd(&sumF[slot * DIM + c + 0], S[0]);
        atomicAdd(&sumF[slot * DIM + c + 1], S[1]);
        atomicAdd(&sumF[slot * DIM + c + 2], S[2]);
        atomicAdd(&sumF[slot * DIM + c + 3], S[3]);
        atomicAdd(&sqF[slot * DIM + c + 0], Q[0]);
        atomicAdd(&sqF[slot * DIM + c + 1], Q[1]);
        atomicAdd(&sqF[slot * DIM + c + 2], Q[2]);
        atomicAdd(&sqF[slot * DIM + c + 3], Q[3]);
    }
}

// ---------------------------------------------------------------------------
// final BN + ReLU with fused finalize
// ---------------------------------------------------------------------------
__global__ __launch_bounds__(256) void bnrelu_kernel(
    float* __restrict__ out,
    const float* __restrict__ sumF, const float* __restrict__ sqF,
    const float* __restrict__ bng, const float* __restrict__ bnb)
{
    __shared__ float scl[DIM], shl[DIM];
    bn_finalize(sumF, sqF, bng, bnb, scl, shl, threadIdx.x);
    __syncthreads();
    int idx = blockIdx.x * blockDim.x + threadIdx.x;
    const int total = N_NODES * (DIM / 4);
    for (int f = idx; f < total; f += gridDim.x * blockDim.x) {
        float4 v = ((float4*)out)[f];
        int c = (f * 4) & (DIM - 1);
        float4 sc = *(const float4*)(scl + c);
        float4 sh = *(const float4*)(shl + c);
        v.x = fmaxf(v.x * sc.x + sh.x, 0.0f);
        v.y = fmaxf(v.y * sc.y + sh.y, 0.0f);
        v.z = fmaxf(v.z * sc.z + sh.z, 0.0f);
        v.w = fmaxf(v.w * sc.w + sh.w, 0.0f);
        ((float4*)out)[f] = v;
    }
}

extern "C" void kernel_launch(void* const* d_in, const int* in_sizes, int n_in,
                              void* d_out, int out_size, void* d_ws, size_t ws_size,
                              hipStream_t stream)
{
    const float* x    = (const float*)d_in[0];
    const int*   ei   = (const int*)  d_in[1];
    const float* ea   = (const float*)d_in[2];
    const int*   vi   = (const int*)  d_in[3];
    const float* vea  = (const float*)d_in[4];
    const float* epsd = (const float*)d_in[5];
    const float* W1d  = (const float*)d_in[6];
    const float* b1d  = (const float*)d_in[7];
    const float* g1d  = (const float*)d_in[8];
    const float* bt1d = (const float*)d_in[9];
    const float* W2d  = (const float*)d_in[10];
    const float* b2d  = (const float*)d_in[11];
    const float* epsu = (const float*)d_in[12];
    const float* W1u  = (const float*)d_in[13];
    const float* b1u  = (const float*)d_in[14];
    const float* g1u  = (const float*)d_in[15];
    const float* bt1u = (const float*)d_in[16];
    const float* W2u  = (const float*)d_in[17];
    const float* b2u  = (const float*)d_in[18];
    const float* bng  = (const float*)d_in[19];
    const float* bnb  = (const float*)d_in[20];
    const float* a1   = (const float*)d_in[21];
    const float* a2   = (const float*)d_in[22];

    float* out = (float*)d_out;

    // ---- workspace layout ----
    char* p = (char*)d_ws;
    unsigned short* hD  = (unsigned short*)p;  p += (size_t)N_NODES * DIM * 2;
    unsigned short* hU  = (unsigned short*)p;  p += (size_t)N_NODES * DIM * 2;
    unsigned short* t1D = (unsigned short*)p;  p += (size_t)N_NODES * DIM * 2;
    unsigned short* t1U = (unsigned short*)p;  p += (size_t)N_NODES * DIM * 2;
    unsigned short* xb  = (unsigned short*)p;  p += (size_t)N_NODES * DIM * 2;
    unsigned short* Wt  = (unsigned short*)p;  p += (size_t)4 * DIM * DIM * 2;
    // zeroed region: stats (6 slices) + offsets
    char* zero_base = p;
    float* stats = (float*)p;                  p += (size_t)6 * NSLOT * DIM * 4;
    int* offD = (int*)p;                       p += (size_t)(N_NODES + 1) * 4;
    int* offU = (int*)p;                       p += (size_t)(N_NODES + 1) * 4;
    size_t zero_bytes = (size_t)(p - zero_base);
    int* curD = (int*)p;                       p += (size_t)N_NODES * 4;
    int* curU = (int*)p;                       p += (size_t)N_NODES * 4;
    char* union_base = p;
    int2* pairsD = (int2*)p;                   p += (size_t)NE * 8;
    int2* pairsU = (int2*)p;                   p += (size_t)NEV * 8;
    size_t need_csr = (size_t)(p - (char*)d_ws);
    float* aggr = (float*)union_base;          // fallback-only, overlaps pairs
    size_t need_fb = (size_t)(union_base - (char*)d_ws) + (size_t)N_NODES * DIM * 4;
    bool use_csr = ws_size >= need_csr;

    float* sumD = stats;
    float* sqD  = stats + 1 * NSLOT * DIM;
    float* sumU = stats + 2 * NSLOT * DIM;
    float* sqU  = stats + 3 * NSLOT * DIM;
    float* sumF = stats + 4 * NSLOT * DIM;
    float* sqF  = stats + 5 * NSLOT * DIM;

    unsigned short* Wt1d = Wt;
    unsigned short* Wt2d = Wt + 1 * (size_t)DIM * DIM;
    unsigned short* Wt1u = Wt + 2 * (size_t)DIM * DIM;
    unsigned short* Wt2u = Wt + 3 * (size_t)DIM * DIM;

    hipMemsetAsync(zero_base, 0, zero_bytes, stream);

    if (use_csr) {
        prep_kernel<<<PREP_W_BLOCKS + PREP_X_BLOCKS + HIST_BLOCKS, 256, 0, stream>>>(
            W1d, W2d, W1u, W2u, Wt, x, xb, ei, vi, offD, offU);
        scan2_kernel<<<2, 1024, 0, stream>>>(offD, curD, offU, curU);
        fill2_kernel<<<(NE + NEV + 255) / 256, 256, 0, stream>>>(
            ei, vi, curD, curU, pairsD, pairsU);
        gather2_kernel<<<N_NODES, 256, 0, stream>>>(
            xb, ea, vea, offD, pairsD, offU, pairsU, epsd, epsu, hD, hU);
    } else if (ws_size >= need_fb) {
        prep_kernel<<<PREP_W_BLOCKS + PREP_X_BLOCKS, 256, 0, stream>>>(
            W1d, W2d, W1u, W2u, Wt, x, xb, ei, vi, offD, offU);
        hipMemsetAsync(aggr, 0, (size_t)N_NODES * DIM * 4, stream);
        scatter_kernel<<<(NE + 3) / 4, 256, 0, stream>>>(x, ea, ei, NE, aggr);
        conv_kernel<<<2048, 256, 0, stream>>>(x, aggr, epsd, hD);
        hipMemsetAsync(aggr, 0, (size_t)N_NODES * DIM * 4, stream);
        scatter_kernel<<<(NEV + 3) / 4, 256, 0, stream>>>(x, vea, vi, NEV, aggr);
        conv_kernel<<<2048, 256, 0, stream>>>(x, aggr, epsu, hU);
    }

    gemm1_both<<<2 * GRID_PER, 256, 0, stream>>>(
        hD, hU, Wt1d, Wt1u, b1d, b1u, t1D, t1U, sumD, sqD, sumU, sqU);

    gemm2_fused<<<GRID_PER, 256, 0, stream>>>(
        t1D, t1U, sumD, sqD, g1d, bt1d, sumU, sqU, g1u, bt1u,
        Wt2d, Wt2u, b2d, b2u, a1, a2, x, out, sumF, sqF);

    bnrelu_kernel<<<2048, 256, 0, stream>>>(out, sumF, sqF, bng, bnb);
}